// Round 3
// baseline (746.245 us; speedup 1.0000x reference)
//
#include <hip/hip_runtime.h>
#include <stdint.h>

#define COLUMNS 1024
#define CPC 16
#define NCELLS 16384
#define SEGS 32
#define SYN 128
#define ACT_TH 10
#define BATCH 4
#define NSEGT (NCELLS*SEGS)           // 524288 segments
#define NPAIR (NSEGT/2)               // 262144 segment-pairs (256 syn)
#define NWAVE 8192
#define PAIRS_PER_WAVE (NPAIR/NWAVE)  // 32

// ---- workspace layout (bytes) ----
#define WS_PRED1 0              // u32[2048]
#define WS_PRED2 8192           // u32[2048]
#define WS_ACT4N 16384          // u32[2048] nibble-packed new activity (atomicOr)
#define WS_CNT   24576          // int[8]
#define WS_ACT8P 32768          // u8[16448] byte activity table (prev)
#define WS_ACT8N 53248          // u8[16448] byte activity table (new)
#define WS_CNT8  73728          // u8[524288] per-segment connected count (tier A)
#define WS_SLOTS 598016         // u16[524288*128] compacted targets (tier A, 134MB)
#define WS_CM    73728          // u8[NPAIR*64] connected nibbles (tier B, 16.8MB)
#define WS_NEED_A (598016 + (size_t)NSEGT * 256)
#define WS_NEED_B (73728 + (size_t)NPAIR * 64)

// act8[cell] = 4-bit batch activity mask (1 byte/cell); 64-byte zero tail is
// the dead slot gathered by disconnected synapses.
__global__ void build_act8(const uint32_t* __restrict__ prev,
                           uint8_t* __restrict__ a8) {
  int i = blockIdx.x * 256 + threadIdx.x;
  if (i >= NCELLS + 64) return;
  uint8_t v = 0;
  if (i < NCELLS) {
#pragma unroll
    for (int b = 0; b < BATCH; ++b)
      v |= (prev[b * NCELLS + i] != 0u ? 1u : 0u) << b;
  }
  a8[i] = v;
}

__global__ void expand_act8(const uint32_t* __restrict__ act4,
                            uint8_t* __restrict__ a8) {
  int i = blockIdx.x * 256 + threadIdx.x;
  if (i >= NCELLS + 64) return;
  uint8_t v = 0;
  if (i < NCELLS) v = (act4[i >> 3] >> ((i & 7) * 4)) & 0xFu;
  a8[i] = v;
}

// Count overlap + predictive-bit emit for one 256-synapse segment-pair.
// COMPACT: also stream-compact connected targets (u16) into slots[seg][.] and
// write cnt8[seg]. WRITECM: write 4-bit connected mask per lane (tier B).
template <bool COMPACT, bool WRITECM>
__device__ __forceinline__ void process_pair(
    int sp, int lane, const uint8_t* act8s, int4 cc, float4 cv, float4 cn,
    uint32_t* __restrict__ pred, uint16_t* __restrict__ slots,
    uint8_t* __restrict__ cnt8, uint8_t* __restrict__ cmb) {
  bool k0 = cv.x + cn.x >= 0.8f;
  bool k1 = cv.y + cn.y >= 0.8f;
  bool k2 = cv.z + cn.z >= 0.8f;
  bool k3 = cv.w + cn.w >= 0.8f;
  uint32_t b0 = act8s[k0 ? cc.x : NCELLS];
  uint32_t b1 = act8s[k1 ? cc.y : NCELLS];
  uint32_t b2 = act8s[k2 ? cc.z : NCELLS];
  uint32_t b3 = act8s[k3 ? cc.w : NCELLS];
  uint32_t t = ((b0 * 0x00204081u) & 0x01010101u) +
               ((b1 * 0x00204081u) & 0x01010101u) +
               ((b2 * 0x00204081u) & 0x01010101u) +
               ((b3 * 0x00204081u) & 0x01010101u);
  if (WRITECM) {
    uint32_t k = (k0 ? 1u : 0u) | (k1 ? 2u : 0u) | (k2 ? 4u : 0u) | (k3 ? 8u : 0u);
    cmb[(size_t)sp * 64 + lane] = (uint8_t)k;
  }
  if (COMPACT) {
    unsigned long long m0 = __ballot(k0), m1 = __ballot(k1);
    unsigned long long m2 = __ballot(k2), m3 = __ballot(k3);
    bool hiHalf = lane >= 32;
    uint32_t h0 = hiHalf ? (uint32_t)(m0 >> 32) : (uint32_t)m0;
    uint32_t h1 = hiHalf ? (uint32_t)(m1 >> 32) : (uint32_t)m1;
    uint32_t h2 = hiHalf ? (uint32_t)(m2 >> 32) : (uint32_t)m2;
    uint32_t h3 = hiHalf ? (uint32_t)(m3 >> 32) : (uint32_t)m3;
    int hl = lane & 31;
    uint32_t below = (hl == 0) ? 0u : (0xFFFFFFFFu >> (32 - hl));
    uint32_t cA = __popc(h0), cB = __popc(h1), cC = __popc(h2);
    int seg = sp * 2 + (hiHalf ? 1 : 0);
    uint16_t* ss = slots + (size_t)seg * 128;
    if (k0) ss[__popc(h0 & below)] = (uint16_t)cc.x;
    if (k1) ss[cA + __popc(h1 & below)] = (uint16_t)cc.y;
    if (k2) ss[cA + cB + __popc(h2 & below)] = (uint16_t)cc.z;
    if (k3) ss[cA + cB + cC + __popc(h3 & below)] = (uint16_t)cc.w;
    if (hl == 0) cnt8[seg] = (uint8_t)(cA + cB + cC + __popc(h3));
  }
  t += __shfl_xor((int)t, 1);
  t += __shfl_xor((int)t, 2);
  t += __shfl_xor((int)t, 4);
  t += __shfl_xor((int)t, 8);
  t += __shfl_xor((int)t, 16);
  if ((lane & 31) == 0) {
    uint32_t pf = 0;
    if (((t >> 0)  & 0xFFu) >= ACT_TH) pf |= 1u;
    if (((t >> 8)  & 0xFFu) >= ACT_TH) pf |= 2u;
    if (((t >> 16) & 0xFFu) >= ACT_TH) pf |= 4u;
    if (((t >> 24) & 0xFFu) >= ACT_TH) pf |= 8u;
    if (pf) {
      int seg = sp * 2 + (lane >> 5);
      int cell = seg >> 5;  // layout [cell][seg]
      uint32_t bit = 1u << (cell & 31);
#pragma unroll
      for (int b = 0; b < BATCH; ++b)
        if ((pf >> b) & 1u)
          atomicOr(&pred[b * (NCELLS / 32) + (cell >> 5)], bit);
    }
  }
}

template <bool COMPACT, bool WRITECM>
__global__ __launch_bounds__(256) void phase_perm(
    const int4* __restrict__ conn4, const float4* __restrict__ vol4,
    const float4* __restrict__ cons4, const uint8_t* __restrict__ g_act8,
    uint32_t* __restrict__ pred, uint16_t* __restrict__ slots,
    uint8_t* __restrict__ cnt8, uint8_t* __restrict__ cmb) {
  __shared__ uint8_t act8s[NCELLS + 64];
  for (int i = threadIdx.x; i < (NCELLS + 64) / 4; i += 256)
    ((uint32_t*)act8s)[i] = ((const uint32_t*)g_act8)[i];
  __syncthreads();
  const int lane = threadIdx.x & 63;
  const int gw = blockIdx.x * 4 + (threadIdx.x >> 6);
  const int sp0 = gw * PAIRS_PER_WAVE;
  const int4* pc = conn4 + (size_t)sp0 * 64 + lane;
  const float4* pv = vol4 + (size_t)sp0 * 64 + lane;
  const float4* pn = cons4 + (size_t)sp0 * 64 + lane;
  int4 cA = pc[0];  float4 vA = pv[0],  nA = pn[0];
  int4 cB = pc[64]; float4 vB = pv[64], nB = pn[64];
#pragma unroll 1
  for (int i = 0; i < PAIRS_PER_WAVE; i += 2) {
    int4 ca = cA; float4 va = vA, na = nA;
    int4 cb = cB; float4 vb = vB, nb = nB;
    if (i + 2 < PAIRS_PER_WAVE) {
      cA = pc[(i + 2) * 64]; vA = pv[(i + 2) * 64]; nA = pn[(i + 2) * 64];
      cB = pc[(i + 3) * 64]; vB = pv[(i + 3) * 64]; nB = pn[(i + 3) * 64];
    }
    process_pair<COMPACT, WRITECM>(sp0 + i, lane, act8s, ca, va, na,
                                   pred, slots, cnt8, cmb);
    process_pair<COMPACT, WRITECM>(sp0 + i + 1, lane, act8s, cb, vb, nb,
                                   pred, slots, cnt8, cmb);
  }
}

// Tier A phase 2: read only the compacted connected targets (~26/segment),
// predicated so untouched slot lines are never fetched.
__global__ __launch_bounds__(256) void phase_compact(
    const uint32_t* __restrict__ slots32, const uint8_t* __restrict__ cnt8,
    const uint8_t* __restrict__ g_act8, uint32_t* __restrict__ pred) {
  __shared__ uint8_t act8s[NCELLS + 64];
  for (int i = threadIdx.x; i < (NCELLS + 64) / 4; i += 256)
    ((uint32_t*)act8s)[i] = ((const uint32_t*)g_act8)[i];
  __syncthreads();
  const int lane = threadIdx.x & 63;
  const int gw = blockIdx.x * 4 + (threadIdx.x >> 6);
  const int hl = lane & 31;
  const int hi = lane >> 5;
#pragma unroll 1
  for (int i = 0; i < 32; ++i) {
    int q = gw * 32 + i;
    int seg = q * 2 + hi;
    uint32_t cnt = cnt8[seg];
    uint32_t sv = 0;
    bool v0 = (uint32_t)(2 * hl) < cnt;
    bool v1 = (uint32_t)(2 * hl + 1) < cnt;
    if (v0) sv = slots32[(size_t)seg * 64 + hl];
    uint32_t a0 = v0 ? (sv & 0xFFFFu) : NCELLS;
    uint32_t a1 = v1 ? (sv >> 16) : NCELLS;
    uint32_t t = (((uint32_t)act8s[a0] * 0x00204081u) & 0x01010101u) +
                 (((uint32_t)act8s[a1] * 0x00204081u) & 0x01010101u);
    if (__any((int)(cnt > 64))) {  // ~never (binomial tail), correctness only
      bool w0 = (uint32_t)(64 + 2 * hl) < cnt;
      bool w1 = (uint32_t)(64 + 2 * hl + 1) < cnt;
      uint32_t sv2 = 0;
      if (w0) sv2 = slots32[(size_t)seg * 64 + 32 + hl];
      uint32_t a2 = w0 ? (sv2 & 0xFFFFu) : NCELLS;
      uint32_t a3 = w1 ? (sv2 >> 16) : NCELLS;
      t += (((uint32_t)act8s[a2] * 0x00204081u) & 0x01010101u) +
           (((uint32_t)act8s[a3] * 0x00204081u) & 0x01010101u);
    }
    t += __shfl_xor((int)t, 1);
    t += __shfl_xor((int)t, 2);
    t += __shfl_xor((int)t, 4);
    t += __shfl_xor((int)t, 8);
    t += __shfl_xor((int)t, 16);
    if (hl == 0) {
      uint32_t pf = 0;
      if (((t >> 0)  & 0xFFu) >= ACT_TH) pf |= 1u;
      if (((t >> 8)  & 0xFFu) >= ACT_TH) pf |= 2u;
      if (((t >> 16) & 0xFFu) >= ACT_TH) pf |= 4u;
      if (((t >> 24) & 0xFFu) >= ACT_TH) pf |= 8u;
      if (pf) {
        int cell = seg >> 5;
        uint32_t bit = 1u << (cell & 31);
#pragma unroll
        for (int b = 0; b < BATCH; ++b)
          if ((pf >> b) & 1u)
            atomicOr(&pred[b * (NCELLS / 32) + (cell >> 5)], bit);
      }
    }
  }
}

// Tier B phase 2: conn + 4-bit connected-mask bytes.
__global__ __launch_bounds__(256) void phase_cm(
    const int4* __restrict__ conn4, const uint8_t* __restrict__ cmb,
    const uint8_t* __restrict__ g_act8, uint32_t* __restrict__ pred) {
  __shared__ uint8_t act8s[NCELLS + 64];
  for (int i = threadIdx.x; i < (NCELLS + 64) / 4; i += 256)
    ((uint32_t*)act8s)[i] = ((const uint32_t*)g_act8)[i];
  __syncthreads();
  const int lane = threadIdx.x & 63;
  const int gw = blockIdx.x * 4 + (threadIdx.x >> 6);
  const int sp0 = gw * PAIRS_PER_WAVE;
#pragma unroll 1
  for (int i = 0; i < PAIRS_PER_WAVE; ++i) {
    int sp = sp0 + i;
    size_t pb = (size_t)sp * 64 + lane;
    uint32_t k = cmb[pb];
    int4 cc = conn4[pb];
    uint32_t b0 = act8s[(k & 1u) ? cc.x : NCELLS];
    uint32_t b1 = act8s[(k & 2u) ? cc.y : NCELLS];
    uint32_t b2 = act8s[(k & 4u) ? cc.z : NCELLS];
    uint32_t b3 = act8s[(k & 8u) ? cc.w : NCELLS];
    uint32_t t = ((b0 * 0x00204081u) & 0x01010101u) +
                 ((b1 * 0x00204081u) & 0x01010101u) +
                 ((b2 * 0x00204081u) & 0x01010101u) +
                 ((b3 * 0x00204081u) & 0x01010101u);
    t += __shfl_xor((int)t, 1);
    t += __shfl_xor((int)t, 2);
    t += __shfl_xor((int)t, 4);
    t += __shfl_xor((int)t, 8);
    t += __shfl_xor((int)t, 16);
    if ((lane & 31) == 0) {
      uint32_t pf = 0;
      if (((t >> 0)  & 0xFFu) >= ACT_TH) pf |= 1u;
      if (((t >> 8)  & 0xFFu) >= ACT_TH) pf |= 2u;
      if (((t >> 16) & 0xFFu) >= ACT_TH) pf |= 4u;
      if (((t >> 24) & 0xFFu) >= ACT_TH) pf |= 8u;
      if (pf) {
        int seg = sp * 2 + (lane >> 5);
        int cell = seg >> 5;
        uint32_t bit = 1u << (cell & 31);
#pragma unroll
        for (int b = 0; b < BATCH; ++b)
          if ((pf >> b) & 1u)
            atomicOr(&pred[b * (NCELLS / 32) + (cell >> 5)], bit);
      }
    }
  }
}

__global__ void mid_kernel(const uint32_t* __restrict__ sdr,
                           const uint32_t* __restrict__ pred1,
                           float* __restrict__ out_active,
                           uint32_t* __restrict__ act4n,
                           int* __restrict__ cnts) {
  int tid = blockIdx.x * blockDim.x + threadIdx.x;
  if (tid >= BATCH * COLUMNS) return;
  int b = tid >> 10, c = tid & 1023;
  uint32_t colbits =
      (pred1[b * (NCELLS / 32) + (c >> 1)] >> ((c & 1) * 16)) & 0xFFFFu;
  bool s = sdr[b * COLUMNS + c] != 0u;
  bool has = colbits != 0u;
  uint32_t act = s ? (has ? colbits : 0xFFFFu) : 0u;
  float* o = out_active + (size_t)b * NCELLS + c * CPC;
#pragma unroll
  for (int j = 0; j < CPC; ++j) o[j] = ((act >> j) & 1u) ? 1.0f : 0.0f;
#pragma unroll
  for (int h = 0; h < 2; ++h) {
    uint32_t bits8 = (act >> (8 * h)) & 0xFFu;
    uint32_t sp = 0;
#pragma unroll
    for (int j = 0; j < 8; ++j) sp |= ((bits8 >> j) & 1u) << (4 * j + b);
    if (sp) atomicOr(&act4n[c * 2 + h], sp);
  }
  unsigned long long sb = __ballot(s);
  unsigned long long pb = __ballot(s && has);
  if ((threadIdx.x & 63) == 0) {
    atomicAdd(&cnts[b], (int)__popcll(sb));
    atomicAdd(&cnts[4 + b], (int)__popcll(pb));
  }
}

__global__ void final_kernel(const uint32_t* __restrict__ sdr,
                             const uint32_t* __restrict__ pred2,
                             const int* __restrict__ cnts,
                             float* __restrict__ out) {
  int tid = blockIdx.x * blockDim.x + threadIdx.x;
  if (tid >= BATCH * COLUMNS) return;
  int b = tid >> 10, c = tid & 1023;
  uint32_t colbits =
      (pred2[b * (NCELLS / 32) + (c >> 1)] >> ((c & 1) * 16)) & 0xFFFFu;
  bool s = sdr[b * COLUMNS + c] != 0u;
  uint32_t pn = s ? colbits : 0u;
  float* o = out + (size_t)BATCH * NCELLS + (size_t)b * NCELLS + c * CPC;
#pragma unroll
  for (int j = 0; j < CPC; ++j) o[j] = ((pn >> j) & 1u) ? 1.0f : 0.0f;
  if (tid < BATCH) {
    int na = cnts[tid], np = cnts[4 + tid];
    out[2 * BATCH * NCELLS + tid] = na > 0 ? (float)np / (float)na : 1.0f;
  }
}

extern "C" void kernel_launch(void* const* d_in, const int* in_sizes, int n_in,
                              void* d_out, int out_size, void* d_ws,
                              size_t ws_size, hipStream_t stream) {
  const uint32_t* sdr = (const uint32_t*)d_in[0];
  const uint32_t* prev = (const uint32_t*)d_in[1];
  const int4* conn4 = (const int4*)d_in[2];
  const float4* vol4 = (const float4*)d_in[3];
  const float4* cons4 = (const float4*)d_in[4];
  float* out = (float*)d_out;
  char* ws = (char*)d_ws;
  uint32_t* pred1 = (uint32_t*)(ws + WS_PRED1);
  uint32_t* pred2 = (uint32_t*)(ws + WS_PRED2);
  uint32_t* act4n = (uint32_t*)(ws + WS_ACT4N);
  int* cnts = (int*)(ws + WS_CNT);
  uint8_t* act8p = (uint8_t*)(ws + WS_ACT8P);
  uint8_t* act8n = (uint8_t*)(ws + WS_ACT8N);
  uint8_t* cnt8 = (uint8_t*)(ws + WS_CNT8);
  uint16_t* slots = (uint16_t*)(ws + WS_SLOTS);
  uint8_t* cmb = (uint8_t*)(ws + WS_CM);
  const bool tierA = ws_size >= WS_NEED_A;
  const bool tierB = ws_size >= WS_NEED_B;

  hipMemsetAsync(ws, 0, 24640, stream);  // pred1, pred2, act4n, cnts
  build_act8<<<(NCELLS + 64 + 255) / 256, 256, 0, stream>>>(prev, act8p);

  if (tierA)
    phase_perm<true, false><<<NWAVE / 4, 256, 0, stream>>>(
        conn4, vol4, cons4, act8p, pred1, slots, cnt8, nullptr);
  else if (tierB)
    phase_perm<false, true><<<NWAVE / 4, 256, 0, stream>>>(
        conn4, vol4, cons4, act8p, pred1, nullptr, nullptr, cmb);
  else
    phase_perm<false, false><<<NWAVE / 4, 256, 0, stream>>>(
        conn4, vol4, cons4, act8p, pred1, nullptr, nullptr, nullptr);

  mid_kernel<<<16, 256, 0, stream>>>(sdr, pred1, out, act4n, cnts);
  expand_act8<<<(NCELLS + 64 + 255) / 256, 256, 0, stream>>>(act4n, act8n);

  if (tierA)
    phase_compact<<<NWAVE / 4, 256, 0, stream>>>(
        (const uint32_t*)slots, cnt8, act8n, pred2);
  else if (tierB)
    phase_cm<<<NWAVE / 4, 256, 0, stream>>>(conn4, cmb, act8n, pred2);
  else
    phase_perm<false, false><<<NWAVE / 4, 256, 0, stream>>>(
        conn4, vol4, cons4, act8n, pred2, nullptr, nullptr, nullptr);

  final_kernel<<<16, 256, 0, stream>>>(sdr, pred2, cnts, out);
}